// Round 5
// baseline (148.152 us; speedup 1.0000x reference)
//
#include <hip/hip_runtime.h>
#include <math.h>

#define BATCH 8192
#define DIM 1024
#define NCLS 1000
#define NPAD 1024         // padded class rows for the bf16 center matrix
#define NPAIRS 499500.0f  // 1000*999/2
#define INTER_TILES 136   // 16*17/2 upper-triangle 64x64 tiles
#define MAXROWS 192       // max rows per class tracked (Poisson mean 8.2, max ~35)

typedef float  f32x4  __attribute__((ext_vector_type(4)));
typedef short  bf16x8 __attribute__((ext_vector_type(8)));

// ---------------- helpers ----------------

__device__ inline float waveAllReduceAdd(float x) {
  #pragma unroll
  for (int m = 32; m > 0; m >>= 1) x += __shfl_xor(x, m);
  return x;
}

// block (256 thr) reduce, broadcast; sm >= 8 floats
__device__ inline float blockReduce1(float x, float* sm) {
  x = waveAllReduceAdd(x);
  int lane = threadIdx.x & 63, wid = threadIdx.x >> 6;
  __syncthreads();
  if (lane == 0) sm[wid] = x;
  __syncthreads();
  return sm[0] + sm[1] + sm[2] + sm[3];
}

__device__ inline unsigned short f2bf(float f) {
  unsigned int u = __float_as_uint(f);
  u += 0x7FFFu + ((u >> 16) & 1u);  // RNE
  return (unsigned short)(u >> 16);
}

// ---------------- K_A: streaming norm pass over all f and fa rows ------------
// 4096 blocks x 4 waves = 16384 wave-units; unit u: row = u>>1, src = u&1.
// Pure BW-bound streaming; reduce tree identical to the previous in-kernel
// computation (bit-identical norms).

__global__ __launch_bounds__(256, 4)
void norms_kernel(const float* __restrict__ feats, const float* __restrict__ featsa,
                  float* __restrict__ invn, float* __restrict__ invna) {
  int lane = threadIdx.x & 63;
  int u = blockIdx.x * 4 + (threadIdx.x >> 6);  // 0..16383
  int row = u >> 1;
  const float* src = (u & 1) ? featsa : feats;
  float* dst = (u & 1) ? invna : invn;
  const float4* rp = (const float4*)(src + (size_t)row * DIM);
  float ss = 0.f;
  #pragma unroll
  for (int i = 0; i < 4; ++i) {
    float4 v = rp[lane + 64 * i];
    ss += v.x * v.x + v.y * v.y + v.z * v.z + v.w * v.w;
  }
  ss = waveAllReduceAdd(ss);
  if (lane == 0) dst[row] = 1.0f / fmaxf(sqrtf(ss), 1e-12f);
}

// ---------------- K_B: center update + intra, norms precomputed --------------
// Block c self-selects its class's rows (label scan, L2 broadcast).
// Pass 1: acc += row * invn[r] -- pure load+FMA, no reduce; two rows in
// flight per wave. Combine -> momentum -> c_new (f32 in LDS, bf16 stored).
// Pass 2: clean + adv dots merged in one loop (reads L3/L2-hot), one reduce
// each, d2 via 1 + ||c||^2 - 2*inv*(x.c). Private per-class output slots.

__global__ __launch_bounds__(256, 4)
void update_centers_intra_kernel(const float* __restrict__ feats,
                                 const float* __restrict__ featsa,
                                 const float* __restrict__ centers,
                                 const int* __restrict__ labels,
                                 const float* __restrict__ invn,
                                 const float* __restrict__ invna,
                                 unsigned short* __restrict__ centers_bf,
                                 float* __restrict__ sqn,
                                 float* __restrict__ pclean,
                                 float* __restrict__ padv) {
  __shared__ float sm[8];
  __shared__ int s_rows[MAXROWS];
  __shared__ int s_cnt;
  __shared__ int s_anynz;
  __shared__ float4 s_acc[4][256];  // 16KB per-wave full-width partial center
  __shared__ float4 s_c[256];       // 4KB: c_new (f32) for pass-2 dots
  int c = blockIdx.x;   // 0..1023
  int tid = threadIdx.x;
  int lane = tid & 63, w = tid >> 6;
  int fi = tid;         // float4 index for full-row ops

  if (c >= NCLS) {  // zero-pad rows so the MFMA tiles can load unguarded
    ((ushort4*)(centers_bf + (size_t)c * DIM))[fi] = make_ushort4(0, 0, 0, 0);
    return;
  }

  // ---- self-select rows of this class ----
  if (tid == 0) { s_cnt = 0; s_anynz = 0; }
  __syncthreads();
  #pragma unroll 4
  for (int j = tid; j < BATCH; j += 256) {
    if (labels[j] == c) {
      int p = atomicAdd(&s_cnt, 1);
      if (p < MAXROWS) s_rows[p] = j;
    }
  }
  __syncthreads();
  int n = min(s_cnt, MAXROWS);

  // ---- pass 1: accumulate normalized rows (no reduces; 2 rows in flight) ----
  float4 acc[4];
  #pragma unroll
  for (int i = 0; i < 4; ++i) acc[i] = make_float4(0.f, 0.f, 0.f, 0.f);

  int t = w;
  for (; t + 4 < n; t += 8) {
    int r0 = s_rows[t], r1 = s_rows[t + 4];
    float iw0 = invn[r0], iw1 = invn[r1];
    const float4* p0 = (const float4*)(feats + (size_t)r0 * DIM);
    const float4* p1 = (const float4*)(feats + (size_t)r1 * DIM);
    float4 v0[4], v1[4];
    #pragma unroll
    for (int i = 0; i < 4; ++i) { v0[i] = p0[lane + 64 * i]; v1[i] = p1[lane + 64 * i]; }
    #pragma unroll
    for (int i = 0; i < 4; ++i) {
      acc[i].x += v0[i].x * iw0 + v1[i].x * iw1;
      acc[i].y += v0[i].y * iw0 + v1[i].y * iw1;
      acc[i].z += v0[i].z * iw0 + v1[i].z * iw1;
      acc[i].w += v0[i].w * iw0 + v1[i].w * iw1;
    }
  }
  if (t < n) {
    int r0 = s_rows[t];
    float iw0 = invn[r0];
    const float4* p0 = (const float4*)(feats + (size_t)r0 * DIM);
    #pragma unroll
    for (int i = 0; i < 4; ++i) {
      float4 v = p0[lane + 64 * i];
      acc[i].x += v.x * iw0; acc[i].y += v.y * iw0;
      acc[i].z += v.z * iw0; acc[i].w += v.w * iw0;
    }
  }

  // ---- combine the 4 waves' partials, momentum, store ----
  #pragma unroll
  for (int i = 0; i < 4; ++i) s_acc[w][lane + 64 * i] = acc[i];
  float4 cv = ((const float4*)(centers + (size_t)c * DIM))[fi];
  if (cv.x != 0.f || cv.y != 0.f || cv.z != 0.f || cv.w != 0.f) s_anynz = 1;
  __syncthreads();
  float4 a0 = s_acc[0][fi], a1 = s_acc[1][fi], a2 = s_acc[2][fi], a3 = s_acc[3][fi];
  float4 sum = make_float4(a0.x + a1.x + a2.x + a3.x, a0.y + a1.y + a2.y + a3.y,
                           a0.z + a1.z + a2.z + a3.z, a0.w + a1.w + a2.w + a3.w);

  float invc = 1.0f / fmaxf((float)n, 1.0f);
  float4 mean = make_float4(sum.x * invc, sum.y * invc, sum.z * invc, sum.w * invc);

  float4 o;
  if (s_anynz) {
    o = make_float4(0.9f * cv.x + 0.1f * mean.x, 0.9f * cv.y + 0.1f * mean.y,
                    0.9f * cv.z + 0.1f * mean.z, 0.9f * cv.w + 0.1f * mean.w);
  } else {
    o = mean;
  }
  if (n == 0) o = cv;

  ((ushort4*)(centers_bf + (size_t)c * DIM))[fi] =
      make_ushort4(f2bf(o.x), f2bf(o.y), f2bf(o.z), f2bf(o.w));
  s_c[fi] = o;

  float sq = blockReduce1(o.x * o.x + o.y * o.y + o.z * o.z + o.w * o.w, sm);
  if (tid == 0) sqn[c] = sq;
  __syncthreads();  // s_c visible to all waves before pass 2

  // ---- pass 2: clean + adv dots (rows L1/L2/L3-hot), merged loop ----
  float sumc = 0.f, suma = 0.f;
  for (int t2 = w; t2 < n; t2 += 4) {
    int r = s_rows[t2];
    const float4* rp = (const float4*)(feats + (size_t)r * DIM);
    const float4* ap = (const float4*)(featsa + (size_t)r * DIM);
    float dotf = 0.f, dota = 0.f;
    #pragma unroll
    for (int i = 0; i < 4; ++i) {
      float4 vf = rp[lane + 64 * i];
      float4 va = ap[lane + 64 * i];
      float4 cc = s_c[lane + 64 * i];
      dotf += vf.x * cc.x + vf.y * cc.y + vf.z * cc.z + vf.w * cc.w;
      dota += va.x * cc.x + va.y * cc.y + va.z * cc.z + va.w * cc.w;
    }
    dotf = waveAllReduceAdd(dotf);
    dota = waveAllReduceAdd(dota);
    if (lane == 0) {
      float d2c = 1.0f + sq - 2.0f * invn[r] * dotf;
      float d2a = 1.0f + sq - 2.0f * invna[r] * dota;
      sumc += sqrtf(fmaxf(d2c, 0.0f));
      suma += sqrtf(fmaxf(d2a, 0.0f));
    }
  }

  float totc = blockReduce1(sumc, sm);  // only lane0s carry nonzero -> correct sum
  float tota = blockReduce1(suma, sm);
  if (tid == 0) { pclean[c] = totc; padv[c] = tota; }
}

// ---------------- K_C: inter loss, 136 upper-triangle 64x64 MFMA tiles -------

__global__ __launch_bounds__(256, 4)
void inter_mfma_kernel(const unsigned short* __restrict__ Cbf,
                       const float* __restrict__ sq,
                       float* __restrict__ pinter) {
  __shared__ float smr[8];
  int tid = threadIdx.x;  // 256
  int bid = blockIdx.x;   // 0..135

  int t = bid;
  int bi = 0;
  while (t >= 16 - bi) { t -= 16 - bi; ++bi; }
  int bj = bi + t;  // bi <= bj, upper triangle of 16x16 tile grid

  int w = tid >> 6;
  int wy = w >> 1, wx = w & 1;
  int lane = tid & 63;
  int m = lane & 15;
  int q = lane >> 4;

  int i0 = bi * 64 + wy * 32;
  int j0 = bj * 64 + wx * 32;

  const unsigned short* arow0 = Cbf + (size_t)(i0 + m) * DIM;
  const unsigned short* arow1 = Cbf + (size_t)(i0 + 16 + m) * DIM;
  const unsigned short* brow0 = Cbf + (size_t)(j0 + m) * DIM;
  const unsigned short* brow1 = Cbf + (size_t)(j0 + 16 + m) * DIM;

  f32x4 acc00 = {0.f, 0.f, 0.f, 0.f}, acc01 = acc00, acc10 = acc00, acc11 = acc00;

  #pragma unroll 4
  for (int k0 = 0; k0 < DIM; k0 += 32) {
    int ko = k0 + q * 8;
    bf16x8 a0 = *(const bf16x8*)(arow0 + ko);
    bf16x8 a1 = *(const bf16x8*)(arow1 + ko);
    bf16x8 b0 = *(const bf16x8*)(brow0 + ko);
    bf16x8 b1 = *(const bf16x8*)(brow1 + ko);
    acc00 = __builtin_amdgcn_mfma_f32_16x16x32_bf16(a0, b0, acc00, 0, 0, 0);
    acc01 = __builtin_amdgcn_mfma_f32_16x16x32_bf16(a0, b1, acc01, 0, 0, 0);
    acc10 = __builtin_amdgcn_mfma_f32_16x16x32_bf16(a1, b0, acc10, 0, 0, 0);
    acc11 = __builtin_amdgcn_mfma_f32_16x16x32_bf16(a1, b1, acc11, 0, 0, 0);
  }

  float local = 0.f;
  int colA = lane & 15;
  int rbase = (lane >> 4) * 4;
  #pragma unroll
  for (int si = 0; si < 2; ++si) {
    #pragma unroll
    for (int sj = 0; sj < 2; ++sj) {
      f32x4 a = (si == 0) ? (sj == 0 ? acc00 : acc01) : (sj == 0 ? acc10 : acc11);
      #pragma unroll
      for (int r = 0; r < 4; ++r) {
        int i = i0 + si * 16 + rbase + r;
        int j = j0 + sj * 16 + colA;
        if (j < NCLS && i < j) {
          float d2 = sq[i] + sq[j] - 2.0f * a[r];
          float d = sqrtf(fmaxf(d2, 0.0f));
          local += fmaxf(1.0f - d, 0.0f);
        }
      }
    }
  }
  float tot = blockReduce1(local, smr);
  if (tid == 0) pinter[bid] = tot;  // private slot, no atomic, no zeroing
}

// ---------------- K_D: final combine ----------------

__global__ void final_kernel(const float* __restrict__ pclean,
                             const float* __restrict__ padv,
                             const float* __restrict__ pinter,
                             float* __restrict__ out) {
  __shared__ float sm[8];
  int t = threadIdx.x;  // 256
  float ci = 0.f;
  for (int i = t; i < NCLS; i += 256) ci += pclean[i] + padv[i];
  float e = (t < INTER_TILES) ? pinter[t] : 0.f;
  ci = blockReduce1(ci, sm);
  e = blockReduce1(e, sm);
  if (t == 0) {
    float intra = ci * (1.0f / (float)BATCH);
    float inter = e / NPAIRS;
    out[0] = intra - 0.5f * inter;  // LAMBDA_INTRA=1, LAMBDA_INTER=0.5
  }
}

// ---------------- launch ----------------

extern "C" void kernel_launch(void* const* d_in, const int* in_sizes, int n_in,
                              void* d_out, int out_size, void* d_ws, size_t ws_size,
                              hipStream_t stream) {
  const float* features     = (const float*)d_in[0];
  const float* features_adv = (const float*)d_in[1];
  const float* centers      = (const float*)d_in[2];
  const int*   labels       = (const int*)d_in[3];
  float* out = (float*)d_out;

  // ws layout: centers_bf[1024*1024 u16] | sqn[1024 f] | invn[8192 f] |
  //            invna[8192 f] | pclean[1024 f] | padv[1024 f] | pinter[256 f]
  unsigned short* centers_bf = (unsigned short*)d_ws;
  float* sqn = (float*)(centers_bf + (size_t)NPAD * DIM);
  float* invn = sqn + 1024;
  float* invna = invn + BATCH;
  float* pclean = invna + BATCH;
  float* padv = pclean + 1024;
  float* pinter = padv + 1024;

  hipLaunchKernelGGL(norms_kernel, dim3(4096), dim3(256), 0, stream,
                     features, features_adv, invn, invna);
  hipLaunchKernelGGL(update_centers_intra_kernel, dim3(NPAD), dim3(256), 0, stream,
                     features, features_adv, centers, labels, invn, invna,
                     centers_bf, sqn, pclean, padv);
  hipLaunchKernelGGL(inter_mfma_kernel, dim3(INTER_TILES), dim3(256), 0, stream,
                     centers_bf, sqn, pinter);
  hipLaunchKernelGGL(final_kernel, dim3(1), dim3(256), 0, stream, pclean, padv,
                     pinter, out);
}